// Round 16
// baseline (3136.269 us; speedup 1.0000x reference)
//
#include <hip/hip_runtime.h>
#include <stdint.h>

// FPS: B=4, N=16*8192=131072 points, C=64, K=128 samples.
// R6 structure (proven pass) + coalesced per-thread transpose:
// each block transposes ITS OWN 512 points into d_ws layout [g][w][c4][lane]
// so round-loop loads are 1024B-contiguous per wave (16 lines/instr vs 64).
// Thread reads back only its own writes -> no sync needed. Distance math
// identical (strided template, numpy pairwise-8 order). Fallback to the
// stride-1 in-place path when ws_size is too small.

#define NB 4
#define NPTS 131072
#define NC 64
#define NC4 16
#define NK 128
#define BPB 256              // blocks per batch
#define NT 256               // threads per block
#define STRIDE (BPB * NT)    // 65536 threads per batch; 2 points per thread
#define TBLK 8192            // float4 per block in transposed ws (512*16)
#define T_OFF 65536          // byte offset of T region in ws (64 KB)

__device__ __forceinline__ void amax2(float& bd, int& bi, float od, int oi) {
  // max by distance; tie -> smaller index (np.argmax first-occurrence)
  if (od > bd || (od == bd && oi < bi)) { bd = od; bi = oi; }
}

// numpy-exact sum((p-c)**2) over 64 f32, pairwise 8-accumulator order.
// S = float4 stride between consecutive channel-groups of one point.
template <int S>
__device__ __forceinline__ float dist_np_s(const float4* __restrict__ p4,
                                           const float4* __restrict__ c4) {
#pragma clang fp contract(off)
  float r0, r1, r2, r3, r4, r5, r6, r7;
  {
    float4 a = p4[0], b = c4[0];
    float dx = a.x - b.x, dy = a.y - b.y, dz = a.z - b.z, dw = a.w - b.w;
    r0 = dx * dx; r1 = dy * dy; r2 = dz * dz; r3 = dw * dw;
    a = p4[S]; b = c4[1];
    dx = a.x - b.x; dy = a.y - b.y; dz = a.z - b.z; dw = a.w - b.w;
    r4 = dx * dx; r5 = dy * dy; r6 = dz * dz; r7 = dw * dw;
  }
#pragma unroll
  for (int blk = 1; blk < 8; ++blk) {
    float4 a = p4[(2 * blk) * S], b = c4[2 * blk];
    float dx = a.x - b.x, dy = a.y - b.y, dz = a.z - b.z, dw = a.w - b.w;
    r0 += dx * dx; r1 += dy * dy; r2 += dz * dz; r3 += dw * dw;
    a = p4[(2 * blk + 1) * S]; b = c4[2 * blk + 1];
    dx = a.x - b.x; dy = a.y - b.y; dz = a.z - b.z; dw = a.w - b.w;
    r4 += dx * dx; r5 += dy * dy; r6 += dz * dz; r7 += dw * dw;
  }
  return ((r0 + r1) + (r2 + r3)) + ((r4 + r5) + (r6 + r7));
}

__global__ __launch_bounds__(NT, 4) void fps_kernel(
    const float* __restrict__ points,         // (B, N, C)
    const int* __restrict__ finit,            // (B,)
    float* __restrict__ out,                  // B*K*C sampled + B*K centroids
    unsigned long long* __restrict__ slots,   // ws: [B][BPB] tagged packs
    unsigned long long* __restrict__ fbc,     // ws: [B] tagged f broadcast
    float4* __restrict__ tb) {                // ws: transposed pts (or null)
  const int bt  = blockIdx.x >> 8;            // batch
  const int ck  = blockIdx.x & (BPB - 1);     // chunk within batch
  const int tid = threadIdx.x;

  __shared__ float cent[NC];
  __shared__ float red_d[NT / 64];
  __shared__ int   red_i[NT / 64];
  __shared__ int   f_sh;
  __shared__ int   hist[NK];

  const float* __restrict__ P = points + (size_t)bt * NPTS * NC;
  unsigned long long* S = slots + bt * BPB;

  const int i0 = ck * NT + tid;         // point 0
  const int i1 = i0 + STRIDE;           // point 1 (i0 < i1 always)
  const int w = tid >> 6, lane = tid & 63;

  // ---- prologue: transpose own 512 points into ws (coalesced writes).
  // Each thread later reads back ONLY its own writes -> no sync needed.
  float4* tb_blk = tb ? tb + (size_t)blockIdx.x * TBLK : nullptr;
  const float4* b0 = nullptr;
  const float4* b1 = nullptr;
  if (tb) {
    {
      const float4* src = (const float4*)(P + (size_t)i0 * NC);
      float4* dst = tb_blk + (size_t)((0 * 4 + w) * NC4) * 64 + lane;
      #pragma unroll
      for (int c = 0; c < NC4; ++c) dst[c * 64] = src[c];
      b0 = dst;
    }
    {
      const float4* src = (const float4*)(P + (size_t)i1 * NC);
      float4* dst = tb_blk + (size_t)((1 * 4 + w) * NC4) * 64 + lane;
      #pragma unroll
      for (int c = 0; c < NC4; ++c) dst[c * 64] = src[c];
      b1 = dst;
    }
  }

  int f = finit[bt];
  if (ck == 0 && tid == 0) hist[0] = f;

  float dloc0 = 1e10f, dloc1 = 1e10f;   // reference INF init

  for (int k = 0; k < NK - 1; ++k) {
    // ---- stage centroid row into LDS
    if (tid < NC4) {
      ((float4*)cent)[tid] = ((const float4*)(P + (size_t)f * NC))[tid];
    }
    __syncthreads();

    // ---- distance update + thread-local argmax (first-occurrence ties)
    float bd = -1.0f; int bi = 0;
    const float4* c4 = (const float4*)cent;
    if (tb) {
      const float d0 = dist_np_s<64>(b0, c4);
      dloc0 = fminf(dloc0, d0);
      if (dloc0 > bd) { bd = dloc0; bi = i0; }
      const float d1 = dist_np_s<64>(b1, c4);
      dloc1 = fminf(dloc1, d1);
      if (dloc1 > bd) { bd = dloc1; bi = i1; }
    } else {
      const float d0 = dist_np_s<1>((const float4*)(P + (size_t)i0 * NC), c4);
      dloc0 = fminf(dloc0, d0);
      if (dloc0 > bd) { bd = dloc0; bi = i0; }
      const float d1 = dist_np_s<1>((const float4*)(P + (size_t)i1 * NC), c4);
      dloc1 = fminf(dloc1, d1);
      if (dloc1 > bd) { bd = dloc1; bi = i1; }
    }

    // ---- wave reduce, then cross-wave via LDS
    #pragma unroll
    for (int off = 32; off > 0; off >>= 1) {
      const float od = __shfl_down(bd, off);
      const int   oi = __shfl_down(bi, off);
      amax2(bd, bi, od, oi);
    }
    if ((tid & 63) == 0) { red_d[tid >> 6] = bd; red_i[tid >> 6] = bi; }
    __syncthreads();

    const unsigned tag = (unsigned)(k + 1);  // unique per round, in [1,127]

    // ---- thread 0 publishes block best (tag+payload in ONE u64, relaxed)
    if (tid == 0) {
      #pragma unroll
      for (int ww = 1; ww < NT / 64; ++ww) amax2(bd, bi, red_d[ww], red_i[ww]);
      // pack: [63:32]=dist bits, [31:24]=tag, [23:0]=idx (N < 2^24)
      // ws poison 0xAA decodes to tag 170, never equal to any real tag.
      const unsigned long long pack =
          ((unsigned long long)__float_as_uint(bd) << 32) |
          ((unsigned long long)(tag & 0xffu) << 24) |
          (unsigned long long)(unsigned)bi;
      __hip_atomic_store(&S[ck], pack, __ATOMIC_RELAXED,
                         __HIP_MEMORY_SCOPE_AGENT);
    }

    if (ck == 0) {
      // ---- leader: wave 0 gathers all 256 slots, reduces, broadcasts f
      if (tid < 64) {
        float pd = -1.0f; int pi = 0;
        #pragma unroll
        for (int s = 0; s < BPB / 64; ++s) {
          const int sl = tid + s * 64;
          unsigned long long v;
          for (;;) {
            v = __hip_atomic_load(&S[sl], __ATOMIC_RELAXED,
                                  __HIP_MEMORY_SCOPE_AGENT);
            if (((unsigned)(v >> 24) & 0xffu) == tag) break;
            __builtin_amdgcn_s_sleep(1);
          }
          amax2(pd, pi, __uint_as_float((unsigned)(v >> 32)),
                (int)(v & 0xffffffu));
        }
        #pragma unroll
        for (int off = 32; off > 0; off >>= 1) {
          const float od = __shfl_down(pd, off);
          const int   oi = __shfl_down(pi, off);
          amax2(pd, pi, od, oi);
        }
        if (tid == 0) {
          f_sh = pi;
          hist[k + 1] = pi;
          const unsigned long long fp =
              ((unsigned long long)(tag & 0xffu) << 24) |
              (unsigned long long)(unsigned)pi;
          __hip_atomic_store(&fbc[bt], fp, __ATOMIC_RELAXED,
                             __HIP_MEMORY_SCOPE_AGENT);
        }
      }
    } else {
      // ---- followers: one thread spins on ONE word
      if (tid == 0) {
        unsigned long long v;
        for (;;) {
          v = __hip_atomic_load(&fbc[bt], __ATOMIC_RELAXED,
                                __HIP_MEMORY_SCOPE_AGENT);
          if (((unsigned)(v >> 24) & 0xffu) == tag) break;
          __builtin_amdgcn_s_sleep(1);
        }
        f_sh = (int)(v & 0xffffffu);
      }
    }
    __syncthreads();
    f = f_sh;
  }

  // ---- epilogue: leader block of each batch writes centroids + sampled rows
  if (ck == 0) {
    for (int e = tid; e < NK; e += NT) {
      out[NB * NK * NC + bt * NK + e] = (float)hist[e];  // exact: idx < 2^24
    }
    for (int e = tid; e < NK * NC; e += NT) {
      const int kk = e >> 6, c = e & (NC - 1);
      out[((size_t)bt * NK + kk) * NC + c] = P[(size_t)hist[kk] * NC + c];
    }
  }
}

extern "C" void kernel_launch(void* const* d_in, const int* in_sizes, int n_in,
                              void* d_out, int out_size, void* d_ws,
                              size_t ws_size, hipStream_t stream) {
  const float* points = (const float*)d_in[0];
  const int* finit = (const int*)d_in[1];
  float* out = (float*)d_out;
  unsigned long long* slots = (unsigned long long*)d_ws;  // 4*256*8 B = 8 KB
  unsigned long long* fbc =
      (unsigned long long*)((char*)d_ws + (size_t)NB * BPB * 8);  // 32 B

  // Transposed-points region: 1024 blocks * 128 KB = 128 MB at ws+64KB.
  const size_t t_bytes = (size_t)NB * BPB * TBLK * sizeof(float4);
  float4* tb = nullptr;
  if (ws_size >= (size_t)T_OFF + t_bytes) {
    tb = (float4*)((char*)d_ws + T_OFF);
  }

  void* args[] = {&points, &finit, &out, &slots, &fbc, &tb};
  hipError_t err = hipLaunchCooperativeKernel(
      (void*)fps_kernel, dim3(NB * BPB), dim3(NT), args, 0, stream);
  if (err != hipSuccess) {
    fps_kernel<<<dim3(NB * BPB), dim3(NT), 0, stream>>>(points, finit, out,
                                                        slots, fbc, tb);
  }
}